// Round 1
// baseline (4499.077 us; speedup 1.0000x reference)
//
#include <hip/hip_runtime.h>
#include <cstdint>
#include <cstddef>

#define DI __device__ __forceinline__

// ---------------- scalar block in workspace ----------------
struct Scal {
  unsigned max_x, max_w1, max_w2, max_wf1, max_wf2;  // float bits (abs-max, >=0)
  float s_in, sw1, sw2, swf1, swf2;
  int   max1; float s1;
  int   max2; float s2;
};

static constexpr int NX   = 32 * 3 * 224 * 224;     // 4,816,896
static constexpr int NY1  = 32 * 32 * 222 * 222;    // 50,466,816
static constexpr int NCONV2 = 32 * 64 * 220 * 55;   // 24,780,800 (4 outputs per thread)

// ---------------- reduction helpers (blockDim == 256) ----------------
DI float wave_maxf(float v) { for (int o = 32; o; o >>= 1) v = fmaxf(v, __shfl_down(v, o, 64)); return v; }
DI int   wave_maxi(int v)   { for (int o = 32; o; o >>= 1) v = max(v, __shfl_down(v, o, 64));   return v; }
DI int   wave_sumi(int v)   { for (int o = 32; o; o >>= 1) v += __shfl_down(v, o, 64);          return v; }

DI float block_maxf(float v) {  // valid in thread 0; all values >= 0
  __shared__ float s[4];
  v = wave_maxf(v);
  int lane = threadIdx.x & 63, w = threadIdx.x >> 6;
  if (!lane) s[w] = v;
  __syncthreads();
  if (threadIdx.x < 64) {
    float t = (threadIdx.x < 4) ? s[threadIdx.x] : 0.f;
    v = wave_maxf(t);
  }
  return v;
}

DI int block_maxi(int v) {  // valid in thread 0; all values >= 0
  __shared__ int s[4];
  v = wave_maxi(v);
  int lane = threadIdx.x & 63, w = threadIdx.x >> 6;
  if (!lane) s[w] = v;
  __syncthreads();
  if (threadIdx.x < 64) {
    int t = (threadIdx.x < 4) ? s[threadIdx.x] : 0;
    v = wave_maxi(t);
  }
  return v;
}

// ---------------- stage kernels ----------------
__global__ void k_absmax_x(const float* __restrict__ x, int n, unsigned* slot) {
  float m = 0.f;
  for (int i = blockIdx.x * blockDim.x + threadIdx.x; i < n; i += gridDim.x * blockDim.x)
    m = fmaxf(m, fabsf(x[i]));
  m = block_maxf(m);
  if (!threadIdx.x) atomicMax(slot, __float_as_uint(m));
}

__global__ void k_absmax_w(const float* __restrict__ w1, const float* __restrict__ w2,
                           const float* __restrict__ wf1, const float* __restrict__ wf2,
                           Scal* sc) {
  const float* p; int n; unsigned* slot;
  if (blockIdx.x == 0)      { p = w1;  n = 864;   slot = &sc->max_w1; }
  else if (blockIdx.x == 1) { p = w2;  n = 18432; slot = &sc->max_w2; }
  else if (blockIdx.x == 2) { p = wf1; n = 8192;  slot = &sc->max_wf1; }
  else                      { p = wf2; n = 1280;  slot = &sc->max_wf2; }
  float m = 0.f;
  for (int i = threadIdx.x; i < n; i += blockDim.x) m = fmaxf(m, fabsf(p[i]));
  m = block_maxf(m);
  if (!threadIdx.x) atomicMax(slot, __float_as_uint(m));
}

__global__ void k_scales(Scal* sc) {
  sc->s_in = fmaxf(__uint_as_float(sc->max_x),  1e-8f) / 7.f;
  sc->sw1  = fmaxf(__uint_as_float(sc->max_w1), 1e-8f) / 7.f;
  sc->sw2  = fmaxf(__uint_as_float(sc->max_w2), 1e-8f) / 7.f;
  sc->swf1 = fmaxf(__uint_as_float(sc->max_wf1),1e-8f) / 7.f;
  sc->swf2 = fmaxf(__uint_as_float(sc->max_wf2),1e-8f) / 7.f;
}

__global__ void k_quant_x(const float* __restrict__ x, signed char* __restrict__ xq,
                          int n, const Scal* __restrict__ sc) {
  float s = sc->s_in;
  for (int i = blockIdx.x * blockDim.x + threadIdx.x; i < n; i += gridDim.x * blockDim.x) {
    float q = rintf(x[i] / s);
    q = fminf(fmaxf(q, -8.f), 7.f);
    xq[i] = (signed char)(int)q;
  }
}

// quantize w1 codes, pack w2 codes 3-per-dword (per (oc,ic,kh)), bias1 ints
__global__ void k_quant_w(const float* __restrict__ w1, const float* __restrict__ w2,
                          const float* __restrict__ b1, const Scal* __restrict__ sc,
                          signed char* __restrict__ qw1, unsigned* __restrict__ w2p,
                          int* __restrict__ bint1) {
  int i = blockIdx.x * blockDim.x + threadIdx.x;
  if (i < 864) {
    float q = rintf(w1[i] / sc->sw1);
    q = fminf(fmaxf(q, -8.f), 7.f);
    qw1[i] = (signed char)(int)q;
  } else if (i < 864 + 6144) {
    int j = i - 864; int base = j * 3; float s = sc->sw2;
    int c[3];
#pragma unroll
    for (int k = 0; k < 3; ++k) {
      float q = rintf(w2[base + k] / s);
      q = fminf(fmaxf(q, -8.f), 7.f);
      c[k] = (int)q;
    }
    w2p[j] = (unsigned)(c[0] & 255) | ((unsigned)(c[1] & 255) << 8) | ((unsigned)(c[2] & 255) << 16);
  } else if (i < 864 + 6144 + 32) {
    int j = i - 7008;
    bint1[j] = (int)rintf(b1[j] / (sc->s_in * sc->sw1));
  }
}

// conv1: 3->32ch, 224^2 -> 222^2. store=0: max pass; store=1: quantize+store uint8 codes
__global__ void k_conv1(const signed char* __restrict__ xq, const signed char* __restrict__ qw1,
                        const int* __restrict__ bint1, const Scal* __restrict__ sc,
                        unsigned char* __restrict__ y1q, int* __restrict__ max1, int store) {
  int idx = blockIdx.x * 256 + threadIdx.x;
  int ow = idx % 222; int t = idx / 222;
  int oh = t % 222;   t /= 222;
  int oc = t & 31, b = t >> 5;
  int acc = bint1[oc];
  const signed char* wp = qw1 + oc * 27;
  const signed char* xp = xq + ((b * 3) * 224 + oh) * 224 + ow;
#pragma unroll
  for (int ic = 0; ic < 3; ++ic) {
#pragma unroll
    for (int kh = 0; kh < 3; ++kh) {
      const signed char* xr = xp + (ic * 224 + kh) * 224;
      acc += (int)xr[0] * (int)wp[0] + (int)xr[1] * (int)wp[1] + (int)xr[2] * (int)wp[2];
      wp += 3;
    }
  }
  if (store) {
    float y = (float)acc * (sc->s_in * sc->sw1);
    float q = rintf(y / sc->s1);
    q = fminf(fmaxf(q, 0.f), 15.f);
    // padded row width 224 for aligned dword reads in conv2
    y1q[((b * 32 + oc) * 222 + oh) * 224 + ow] = (unsigned char)(int)q;
  } else {
    int m = block_maxi(max(acc, 0));
    if (!threadIdx.x) atomicMax(max1, m);
  }
}

__global__ void k_fin1(Scal* sc, const float* __restrict__ b2, int* __restrict__ bint2) {
  float sc1 = sc->s_in * sc->sw1;
  float s1 = fmaxf((float)sc->max1 * sc1, 1e-8f) / 15.f;
  if (!threadIdx.x) sc->s1 = s1;
  float sb = s1 * sc->sw2;
  bint2[threadIdx.x] = (int)rintf(b2[threadIdx.x] / sb);
}

// conv2: 32->64ch, 222^2 -> 220^2. 4 outputs per thread along ow. Exact int accum.
__global__ void k_conv2(const unsigned char* __restrict__ y1q, const unsigned* __restrict__ w2p,
                        const int* __restrict__ bint2, unsigned short* __restrict__ y2,
                        int* __restrict__ max2) {
  int idx = blockIdx.x * 256 + threadIdx.x;
  int g = idx % 55; int t = idx / 55;
  int oh = t % 220; t /= 220;
  int oc = t & 63, b = t >> 6;
  int ow = g * 4;
  int bias = bint2[oc];
  int a0 = bias, a1 = bias, a2 = bias, a3 = bias;
  const unsigned char* xbase = y1q + ((b * 32) * 222 + oh) * 224 + ow;
  const unsigned* wp = w2p + oc * 96;
  for (int ic = 0; ic < 32; ++ic) {
    const unsigned char* xr = xbase + ic * (222 * 224);
#pragma unroll
    for (int kh = 0; kh < 3; ++kh) {
      const unsigned* p = (const unsigned*)(xr + kh * 224);  // 4-byte aligned (224%4==0, ow%4==0)
      unsigned lo = p[0], hi = p[1];
      unsigned w = wp[ic * 3 + kh];
      int w0 = (int)(signed char)(w & 255);
      int w1 = (int)(signed char)((w >> 8) & 255);
      int w2v = (int)(signed char)((w >> 16) & 255);
      int x0 = (int)(lo & 255), x1 = (int)((lo >> 8) & 255);
      int x2 = (int)((lo >> 16) & 255), x3 = (int)(lo >> 24);
      int x4 = (int)(hi & 255), x5 = (int)((hi >> 8) & 255);
      a0 += x0 * w0 + x1 * w1 + x2 * w2v;
      a1 += x1 * w0 + x2 * w1 + x3 * w2v;
      a2 += x2 * w0 + x3 * w1 + x4 * w2v;
      a3 += x3 * w0 + x4 * w1 + x5 * w2v;
    }
  }
  size_t off = ((size_t)(b * 64 + oc) * 220 + oh) * 220 + ow;
  uint2 st;
  st.x = (unsigned)min(max(a0, 0), 65535) | ((unsigned)min(max(a1, 0), 65535) << 16);
  st.y = (unsigned)min(max(a2, 0), 65535) | ((unsigned)min(max(a3, 0), 65535) << 16);
  *(uint2*)(y2 + off) = st;
  int m = max(max(a0, a1), max(a2, a3));
  m = block_maxi(max(m, 0));
  if (!threadIdx.x) atomicMax(max2, m);
}

__global__ void k_fin2(Scal* sc) {
  sc->s2 = fmaxf((float)sc->max2 * (sc->s1 * sc->sw2), 1e-8f) / 15.f;
}

// quantize y2 + global average pool per (b, oc)
__global__ void k_pool(const unsigned short* __restrict__ y2, const Scal* __restrict__ sc,
                       float* __restrict__ pooled) {
  int bc = blockIdx.x;  // 0..2047 = b*64+oc
  const unsigned short* p = y2 + (size_t)bc * 48400;
  float sc2 = sc->s1 * sc->sw2, s2 = sc->s2;
  int sum = 0;
  for (int i = threadIdx.x; i < 48400; i += 256) {
    float y = (float)p[i] * sc2;
    float q = rintf(y / s2);
    q = fminf(fmaxf(q, 0.f), 15.f);
    sum += (int)q;
  }
  sum = wave_sumi(sum);
  __shared__ int s[4];
  int lane = threadIdx.x & 63, w = threadIdx.x >> 6;
  if (!lane) s[w] = sum;
  __syncthreads();
  if (threadIdx.x < 64) {
    int v = (threadIdx.x < 4) ? s[threadIdx.x] : 0;
    v = wave_sumi(v);
    if (!threadIdx.x) pooled[bc] = ((float)v * s2) / 48400.0f;
  }
}

// whole FC head + log_softmax in one block
__global__ void k_fc(const float* __restrict__ pooled, const float* __restrict__ wf1,
                     const float* __restrict__ bf1, const float* __restrict__ wf2,
                     const float* __restrict__ bf2, const Scal* __restrict__ sc,
                     float* __restrict__ out) {
  __shared__ float pl[2048];
  __shared__ float wq1[8192];
  __shared__ float y3[4096];
  __shared__ float zz[320];
  __shared__ float s3sh;
  int tid = threadIdx.x;
  float swf1 = sc->swf1, swf2 = sc->swf2, s2 = sc->s2;
  for (int i = tid; i < 2048; i += 256) pl[i] = pooled[i];
  for (int i = tid; i < 8192; i += 256) {
    float q = rintf(wf1[i] / swf1);
    q = fminf(fmaxf(q, -8.f), 7.f);
    wq1[i] = q * swf1;
  }
  __syncthreads();
  float sb1 = s2 * swf1;
  float lmax = 0.f;
  for (int o = tid; o < 4096; o += 256) {
    int b = o >> 7, j = o & 127;
    float acc = rintf(bf1[j] / sb1) * sb1;
    const float* wrow = &wq1[j * 64];
    const float* xrow = &pl[b * 64];
#pragma unroll 16
    for (int k = 0; k < 64; ++k) acc += xrow[k] * wrow[k];
    float r = fmaxf(acc, 0.f);
    y3[o] = r;
    lmax = fmaxf(lmax, r);
  }
  float m = block_maxf(lmax);  // contains a __syncthreads (after y3 writes)
  if (!tid) s3sh = fmaxf(m, 1e-8f) / 15.f;
  __syncthreads();
  float s3 = s3sh;
  float sb2 = s3 * swf2;
  for (int o = tid; o < 320; o += 256) {
    int b = o / 10, j = o - b * 10;
    float acc = rintf(bf2[j] / sb2) * sb2;
    const float* yy = &y3[b * 128];
    const float* wrow = &wf2[j * 128];
    for (int k = 0; k < 128; ++k) {
      float q = rintf(yy[k] / s3);
      q = fminf(fmaxf(q, 0.f), 15.f);
      float wv = rintf(wrow[k] / swf2);
      wv = fminf(fmaxf(wv, -8.f), 7.f);
      acc += (q * s3) * (wv * swf2);
    }
    zz[o] = acc;
  }
  __syncthreads();
  if (tid < 32) {
    const float* z = &zz[tid * 10];
    float mm = z[0];
    for (int k = 1; k < 10; ++k) mm = fmaxf(mm, z[k]);
    float ssum = 0.f;
    for (int k = 0; k < 10; ++k) ssum += expf(z[k] - mm);
    float l = mm + logf(ssum);
    for (int k = 0; k < 10; ++k) out[tid * 10 + k] = z[k] - l;
  }
}

extern "C" void kernel_launch(void* const* d_in, const int* in_sizes, int n_in,
                              void* d_out, int out_size, void* d_ws, size_t ws_size,
                              hipStream_t stream) {
  const float* x   = (const float*)d_in[0];
  const float* w1  = (const float*)d_in[1];
  const float* b1  = (const float*)d_in[2];
  const float* w2  = (const float*)d_in[3];
  const float* b2  = (const float*)d_in[4];
  const float* wf1 = (const float*)d_in[5];
  const float* bf1 = (const float*)d_in[6];
  const float* wf2 = (const float*)d_in[7];
  const float* bf2 = (const float*)d_in[8];
  float* out = (float*)d_out;

  char* ws = (char*)d_ws;
  Scal* sc = (Scal*)ws;
  size_t off = 1024;
  signed char* xq = (signed char*)(ws + off);   off += (size_t)NX;            // 4,816,896
  signed char* qw1 = (signed char*)(ws + off);  off += 1024;                  // 864 used
  unsigned* w2p = (unsigned*)(ws + off);        off += 6144 * 4;              // packed conv2 weights
  int* bint1 = (int*)(ws + off);                off += 256;
  int* bint2 = (int*)(ws + off);                off += 256;
  unsigned char* y1q = (unsigned char*)(ws + off); off += (size_t)32 * 32 * 222 * 224; // 50,921,472 (padded W)
  unsigned short* y2 = (unsigned short*)(ws + off); off += (size_t)32 * 64 * 220 * 220 * 2; // 198,246,400
  float* pooled = (float*)(ws + off);           off += 8192;
  (void)ws_size; (void)in_sizes; (void)n_in; (void)out_size;

  hipMemsetAsync(sc, 0, 1024, stream);
  k_absmax_x<<<1024, 256, 0, stream>>>(x, NX, &sc->max_x);
  k_absmax_w<<<4, 256, 0, stream>>>(w1, w2, wf1, wf2, sc);
  k_scales<<<1, 1, 0, stream>>>(sc);
  k_quant_x<<<2048, 256, 0, stream>>>(x, xq, NX, sc);
  k_quant_w<<<28, 256, 0, stream>>>(w1, w2, b1, sc, qw1, w2p, bint1);
  k_conv1<<<NY1 / 256, 256, 0, stream>>>(xq, qw1, bint1, sc, y1q, &sc->max1, 0);  // max pass
  k_fin1<<<1, 64, 0, stream>>>(sc, b2, bint2);
  k_conv1<<<NY1 / 256, 256, 0, stream>>>(xq, qw1, bint1, sc, y1q, &sc->max1, 1);  // store pass
  k_conv2<<<NCONV2 / 256, 256, 0, stream>>>(y1q, w2p, bint2, y2, &sc->max2);
  k_fin2<<<1, 1, 0, stream>>>(sc);
  k_pool<<<2048, 256, 0, stream>>>(y2, sc, pooled);
  k_fc<<<1, 256, 0, stream>>>(pooled, wf1, bf1, wf2, bf2, sc, out);
}

// Round 2
// 2016.574 us; speedup vs baseline: 2.2311x; 2.2311x over previous
//
#include <hip/hip_runtime.h>
#include <cstdint>
#include <cstddef>

#define DI __device__ __forceinline__

// ---------------- scalar block in workspace ----------------
struct Scal {
  unsigned max_x, max_w1, max_w2, max_wf1, max_wf2;  // float bits (abs-max, >=0)
  float s_in, sw1, sw2, swf1, swf2;
  int   max1; float s1;
  int   max2; float s2;
};

static constexpr int NX   = 32 * 3 * 224 * 224;     // 4,816,896
static constexpr int NP1  = 32 * 32 * 222 * 224;    // 50,921,472 padded conv1 outputs
static constexpr int NCONV1 = 32 * 32 * 222 * 28;   // 6,365,184 threads (8 outputs each)
static constexpr int NCONV2 = 32 * 64 * 220 * 55;   // 24,780,800 (4 outputs per thread)

// ---------------- reduction helpers (blockDim == 256) ----------------
DI float wave_maxf(float v) { for (int o = 32; o; o >>= 1) v = fmaxf(v, __shfl_down(v, o, 64)); return v; }
DI int   wave_maxi(int v)   { for (int o = 32; o; o >>= 1) v = max(v, __shfl_down(v, o, 64));   return v; }
DI int   wave_sumi(int v)   { for (int o = 32; o; o >>= 1) v += __shfl_down(v, o, 64);          return v; }

DI float block_maxf(float v) {  // valid in thread 0; all values >= 0
  __shared__ float s[4];
  v = wave_maxf(v);
  int lane = threadIdx.x & 63, w = threadIdx.x >> 6;
  if (!lane) s[w] = v;
  __syncthreads();
  if (threadIdx.x < 64) {
    float t = (threadIdx.x < 4) ? s[threadIdx.x] : 0.f;
    v = wave_maxf(t);
  }
  return v;
}

DI int block_maxi(int v) {  // valid in thread 0; all values >= 0
  __shared__ int s[4];
  v = wave_maxi(v);
  int lane = threadIdx.x & 63, w = threadIdx.x >> 6;
  if (!lane) s[w] = v;
  __syncthreads();
  if (threadIdx.x < 64) {
    int t = (threadIdx.x < 4) ? s[threadIdx.x] : 0;
    v = wave_maxi(t);
  }
  return v;
}

// ---------------- stage kernels ----------------
__global__ void k_absmax_x(const float* __restrict__ x, int n, unsigned* slot) {
  float m = 0.f;
  for (int i = blockIdx.x * blockDim.x + threadIdx.x; i < n; i += gridDim.x * blockDim.x)
    m = fmaxf(m, fabsf(x[i]));
  m = block_maxf(m);
  if (!threadIdx.x) atomicMax(slot, __float_as_uint(m));
}

__global__ void k_absmax_w(const float* __restrict__ w1, const float* __restrict__ w2,
                           const float* __restrict__ wf1, const float* __restrict__ wf2,
                           Scal* sc) {
  const float* p; int n; unsigned* slot;
  if (blockIdx.x == 0)      { p = w1;  n = 864;   slot = &sc->max_w1; }
  else if (blockIdx.x == 1) { p = w2;  n = 18432; slot = &sc->max_w2; }
  else if (blockIdx.x == 2) { p = wf1; n = 8192;  slot = &sc->max_wf1; }
  else                      { p = wf2; n = 1280;  slot = &sc->max_wf2; }
  float m = 0.f;
  for (int i = threadIdx.x; i < n; i += blockDim.x) m = fmaxf(m, fabsf(p[i]));
  m = block_maxf(m);
  if (!threadIdx.x) atomicMax(slot, __float_as_uint(m));
}

__global__ void k_scales(Scal* sc) {
  sc->s_in = fmaxf(__uint_as_float(sc->max_x),  1e-8f) / 7.f;
  sc->sw1  = fmaxf(__uint_as_float(sc->max_w1), 1e-8f) / 7.f;
  sc->sw2  = fmaxf(__uint_as_float(sc->max_w2), 1e-8f) / 7.f;
  sc->swf1 = fmaxf(__uint_as_float(sc->max_wf1),1e-8f) / 7.f;
  sc->swf2 = fmaxf(__uint_as_float(sc->max_wf2),1e-8f) / 7.f;
}

__global__ void k_quant_x(const float* __restrict__ x, signed char* __restrict__ xq,
                          int n, const Scal* __restrict__ sc) {
  float s = sc->s_in;
  for (int i = blockIdx.x * blockDim.x + threadIdx.x; i < n; i += gridDim.x * blockDim.x) {
    float q = rintf(x[i] / s);
    q = fminf(fmaxf(q, -8.f), 7.f);
    xq[i] = (signed char)(int)q;
  }
}

// quantize w1 codes, pack w2 codes 3-per-dword (per (oc,ic,kh)), bias1 ints
__global__ void k_quant_w(const float* __restrict__ w1, const float* __restrict__ w2,
                          const float* __restrict__ b1, const Scal* __restrict__ sc,
                          signed char* __restrict__ qw1, unsigned* __restrict__ w2p,
                          int* __restrict__ bint1) {
  int i = blockIdx.x * blockDim.x + threadIdx.x;
  if (i < 864) {
    float q = rintf(w1[i] / sc->sw1);
    q = fminf(fmaxf(q, -8.f), 7.f);
    qw1[i] = (signed char)(int)q;
  } else if (i < 864 + 6144) {
    int j = i - 864; int base = j * 3; float s = sc->sw2;
    int c[3];
#pragma unroll
    for (int k = 0; k < 3; ++k) {
      float q = rintf(w2[base + k] / s);
      q = fminf(fmaxf(q, -8.f), 7.f);
      c[k] = (int)q;
    }
    w2p[j] = (unsigned)(c[0] & 255) | ((unsigned)(c[1] & 255) << 8) | ((unsigned)(c[2] & 255) << 16);
  } else if (i < 864 + 6144 + 32) {
    int j = i - 7008;
    bint1[j] = (int)rintf(b1[j] / (sc->s_in * sc->sw1));
  }
}

// conv1 fused single pass: 3->32ch, 224^2 -> 222^2. 8 outputs/thread along ow.
// Stores raw int16 acc (padded row width 224); block-reduced running max of relu(acc).
__global__ void __launch_bounds__(256) k_conv1(
    const signed char* __restrict__ xq, const signed char* __restrict__ qw1,
    const int* __restrict__ bint1, short* __restrict__ y1acc, int* __restrict__ max1) {
  __shared__ signed char lw[864];
  int tid = threadIdx.x;
  if (tid < 216) ((int*)lw)[tid] = ((const int*)qw1)[tid];
  __syncthreads();

  int idx = blockIdx.x * 256 + tid;
  int g = idx % 28; int t = idx / 28;
  int oh = t % 222; t /= 222;
  int oc = t & 31, b = t >> 5;

  int w[9][3];
  {
    const signed char* wp = lw + oc * 27;
#pragma unroll
    for (int r = 0; r < 9; ++r)
#pragma unroll
      for (int k = 0; k < 3; ++k) w[r][k] = (int)wp[r * 3 + k];
  }
  int bias = bint1[oc];
  int acc[8];
#pragma unroll
  for (int j = 0; j < 8; ++j) acc[j] = bias;

  const signed char* xp = xq + ((b * 3) * 224 + oh) * 224 + g * 8;
#pragma unroll
  for (int ic = 0; ic < 3; ++ic) {
#pragma unroll
    for (int kh = 0; kh < 3; ++kh) {
      const signed char* xr = xp + (ic * 224 + kh) * 224;
      uint2 lo = *(const uint2*)xr;              // bytes 0..7   (8B aligned)
      unsigned hi = *(const unsigned*)(xr + 8);  // bytes 8..11  (4B aligned)
      int xv[10];
#pragma unroll
      for (int k = 0; k < 4; ++k) xv[k]     = (int)(signed char)(lo.x >> (8 * k));
#pragma unroll
      for (int k = 0; k < 4; ++k) xv[4 + k] = (int)(signed char)(lo.y >> (8 * k));
      xv[8] = (int)(signed char)(hi);
      xv[9] = (int)(signed char)(hi >> 8);
      int r = ic * 3 + kh;
      int w0 = w[r][0], w1 = w[r][1], w2 = w[r][2];
#pragma unroll
      for (int j = 0; j < 8; ++j)
        acc[j] += xv[j] * w0 + xv[j + 1] * w1 + xv[j + 2] * w2;
    }
  }

  // store 8 int16 (16B aligned: row stride 224 el, g*8 offset)
  size_t off = ((size_t)((b * 32 + oc) * 222 + oh)) * 224 + g * 8;
  uint4 st;
  st.x = ((unsigned)(unsigned short)acc[0]) | ((unsigned)(unsigned short)acc[1] << 16);
  st.y = ((unsigned)(unsigned short)acc[2]) | ((unsigned)(unsigned short)acc[3] << 16);
  st.z = ((unsigned)(unsigned short)acc[4]) | ((unsigned)(unsigned short)acc[5] << 16);
  st.w = ((unsigned)(unsigned short)acc[6]) | ((unsigned)(unsigned short)acc[7] << 16);
  *(uint4*)(y1acc + off) = st;

  // max over VALID columns only (col = 8g+j < 222)
  int m = 0;
#pragma unroll
  for (int j = 0; j < 8; ++j) if (g * 8 + j < 222) m = max(m, acc[j]);
  m = block_maxi(m);
  if (!tid) atomicMax(max1, m);
}

__global__ void k_fin1(Scal* sc, const float* __restrict__ b2, int* __restrict__ bint2) {
  float sc1 = sc->s_in * sc->sw1;
  float s1 = fmaxf((float)sc->max1 * sc1, 1e-8f) / 15.f;
  if (!threadIdx.x) sc->s1 = s1;
  float sb = s1 * sc->sw2;
  bint2[threadIdx.x] = (int)rintf(b2[threadIdx.x] / sb);
}

// int16 acc -> uint8 relu4 codes, elementwise over padded layout, 8 elems/thread
__global__ void k_requant(const short* __restrict__ y1acc, const Scal* __restrict__ sc,
                          unsigned char* __restrict__ y1q) {
  int i = blockIdx.x * 256 + threadIdx.x;
  float sc1 = sc->s_in * sc->sw1, s1 = sc->s1;
  uint4 v = *(const uint4*)(y1acc + (size_t)i * 8);
  unsigned words[4] = {v.x, v.y, v.z, v.w};
  unsigned outw[2] = {0, 0};
#pragma unroll
  for (int k = 0; k < 8; ++k) {
    int a = (int)(short)(words[k >> 1] >> (16 * (k & 1)));
    float y = (float)a * sc1;
    float q = rintf(y / s1);
    q = fminf(fmaxf(q, 0.f), 15.f);
    outw[k >> 2] |= ((unsigned)(int)q) << (8 * (k & 3));
  }
  *(uint2*)(y1q + (size_t)i * 8) = make_uint2(outw[0], outw[1]);
}

// conv2: 32->64ch, 222^2 -> 220^2. 4 outputs per thread along ow. Exact int accum.
__global__ void k_conv2(const unsigned char* __restrict__ y1q, const unsigned* __restrict__ w2p,
                        const int* __restrict__ bint2, unsigned short* __restrict__ y2,
                        int* __restrict__ max2) {
  int idx = blockIdx.x * 256 + threadIdx.x;
  int g = idx % 55; int t = idx / 55;
  int oh = t % 220; t /= 220;
  int oc = t & 63, b = t >> 6;
  int ow = g * 4;
  int bias = bint2[oc];
  int a0 = bias, a1 = bias, a2 = bias, a3 = bias;
  const unsigned char* xbase = y1q + ((b * 32) * 222 + oh) * 224 + ow;
  const unsigned* wp = w2p + oc * 96;
  for (int ic = 0; ic < 32; ++ic) {
    const unsigned char* xr = xbase + ic * (222 * 224);
#pragma unroll
    for (int kh = 0; kh < 3; ++kh) {
      const unsigned* p = (const unsigned*)(xr + kh * 224);  // 4-byte aligned
      unsigned lo = p[0], hi = p[1];
      unsigned w = wp[ic * 3 + kh];
      int w0 = (int)(signed char)(w & 255);
      int w1 = (int)(signed char)((w >> 8) & 255);
      int w2v = (int)(signed char)((w >> 16) & 255);
      int x0 = (int)(lo & 255), x1 = (int)((lo >> 8) & 255);
      int x2 = (int)((lo >> 16) & 255), x3 = (int)(lo >> 24);
      int x4 = (int)(hi & 255), x5 = (int)((hi >> 8) & 255);
      a0 += x0 * w0 + x1 * w1 + x2 * w2v;
      a1 += x1 * w0 + x2 * w1 + x3 * w2v;
      a2 += x2 * w0 + x3 * w1 + x4 * w2v;
      a3 += x3 * w0 + x4 * w1 + x5 * w2v;
    }
  }
  size_t off = ((size_t)(b * 64 + oc) * 220 + oh) * 220 + ow;
  uint2 st;
  st.x = (unsigned)min(max(a0, 0), 65535) | ((unsigned)min(max(a1, 0), 65535) << 16);
  st.y = (unsigned)min(max(a2, 0), 65535) | ((unsigned)min(max(a3, 0), 65535) << 16);
  *(uint2*)(y2 + off) = st;
  int m = max(max(a0, a1), max(a2, a3));
  m = block_maxi(max(m, 0));
  if (!threadIdx.x) atomicMax(max2, m);
}

__global__ void k_fin2(Scal* sc) {
  sc->s2 = fmaxf((float)sc->max2 * (sc->s1 * sc->sw2), 1e-8f) / 15.f;
}

// quantize y2 + global average pool per (b, oc); vectorized uint4 (8 x u16) loads
__global__ void k_pool(const unsigned short* __restrict__ y2, const Scal* __restrict__ sc,
                       float* __restrict__ pooled) {
  int bc = blockIdx.x;  // 0..2047 = b*64+oc
  const unsigned short* p = y2 + (size_t)bc * 48400;
  float sc2 = sc->s1 * sc->sw2, s2 = sc->s2;
  int sum = 0;
  for (int i = threadIdx.x; i < 6050; i += 256) {
    uint4 v = *(const uint4*)(p + (size_t)i * 8);
    unsigned words[4] = {v.x, v.y, v.z, v.w};
#pragma unroll
    for (int k = 0; k < 8; ++k) {
      int a = (int)(unsigned short)(words[k >> 1] >> (16 * (k & 1)));
      float y = (float)a * sc2;
      float q = rintf(y / s2);
      q = fminf(fmaxf(q, 0.f), 15.f);
      sum += (int)q;
    }
  }
  sum = wave_sumi(sum);
  __shared__ int s[4];
  int lane = threadIdx.x & 63, w = threadIdx.x >> 6;
  if (!lane) s[w] = sum;
  __syncthreads();
  if (threadIdx.x < 64) {
    int v = (threadIdx.x < 4) ? s[threadIdx.x] : 0;
    v = wave_sumi(v);
    if (!threadIdx.x) pooled[bc] = ((float)v * s2) / 48400.0f;
  }
}

// whole FC head + log_softmax in one block
__global__ void k_fc(const float* __restrict__ pooled, const float* __restrict__ wf1,
                     const float* __restrict__ bf1, const float* __restrict__ wf2,
                     const float* __restrict__ bf2, const Scal* __restrict__ sc,
                     float* __restrict__ out) {
  __shared__ float pl[2048];
  __shared__ float wq1[8192];
  __shared__ float y3[4096];
  __shared__ float zz[320];
  __shared__ float s3sh;
  int tid = threadIdx.x;
  float swf1 = sc->swf1, swf2 = sc->swf2, s2 = sc->s2;
  for (int i = tid; i < 2048; i += 256) pl[i] = pooled[i];
  for (int i = tid; i < 8192; i += 256) {
    float q = rintf(wf1[i] / swf1);
    q = fminf(fmaxf(q, -8.f), 7.f);
    wq1[i] = q * swf1;
  }
  __syncthreads();
  float sb1 = s2 * swf1;
  float lmax = 0.f;
  for (int o = tid; o < 4096; o += 256) {
    int b = o >> 7, j = o & 127;
    float acc = rintf(bf1[j] / sb1) * sb1;
    const float* wrow = &wq1[j * 64];
    const float* xrow = &pl[b * 64];
#pragma unroll 16
    for (int k = 0; k < 64; ++k) acc += xrow[k] * wrow[k];
    float r = fmaxf(acc, 0.f);
    y3[o] = r;
    lmax = fmaxf(lmax, r);
  }
  float m = block_maxf(lmax);  // contains a __syncthreads (after y3 writes)
  if (!tid) s3sh = fmaxf(m, 1e-8f) / 15.f;
  __syncthreads();
  float s3 = s3sh;
  float sb2 = s3 * swf2;
  for (int o = tid; o < 320; o += 256) {
    int b = o / 10, j = o - b * 10;
    float acc = rintf(bf2[j] / sb2) * sb2;
    const float* yy = &y3[b * 128];
    const float* wrow = &wf2[j * 128];
    for (int k = 0; k < 128; ++k) {
      float q = rintf(yy[k] / s3);
      q = fminf(fmaxf(q, 0.f), 15.f);
      float wv = rintf(wrow[k] / swf2);
      wv = fminf(fmaxf(wv, -8.f), 7.f);
      acc += (q * s3) * (wv * swf2);
    }
    zz[o] = acc;
  }
  __syncthreads();
  if (tid < 32) {
    const float* z = &zz[tid * 10];
    float mm = z[0];
    for (int k = 1; k < 10; ++k) mm = fmaxf(mm, z[k]);
    float ssum = 0.f;
    for (int k = 0; k < 10; ++k) ssum += expf(z[k] - mm);
    float l = mm + logf(ssum);
    for (int k = 0; k < 10; ++k) out[tid * 10 + k] = z[k] - l;
  }
}

extern "C" void kernel_launch(void* const* d_in, const int* in_sizes, int n_in,
                              void* d_out, int out_size, void* d_ws, size_t ws_size,
                              hipStream_t stream) {
  const float* x   = (const float*)d_in[0];
  const float* w1  = (const float*)d_in[1];
  const float* b1  = (const float*)d_in[2];
  const float* w2  = (const float*)d_in[3];
  const float* b2  = (const float*)d_in[4];
  const float* wf1 = (const float*)d_in[5];
  const float* bf1 = (const float*)d_in[6];
  const float* wf2 = (const float*)d_in[7];
  const float* bf2 = (const float*)d_in[8];
  float* out = (float*)d_out;

  char* ws = (char*)d_ws;
  Scal* sc = (Scal*)ws;
  size_t off = 1024;
  signed char* xq = (signed char*)(ws + off);   off += (size_t)NX + 256;      // +slack for 12B edge reads
  off = (off + 255) & ~(size_t)255;
  signed char* qw1 = (signed char*)(ws + off);  off += 1024;
  unsigned* w2p = (unsigned*)(ws + off);        off += 6144 * 4;
  int* bint1 = (int*)(ws + off);                off += 256;
  int* bint2 = (int*)(ws + off);                off += 256;
  unsigned char* y1q = (unsigned char*)(ws + off); off += (size_t)NP1;        // 50,921,472
  off = (off + 255) & ~(size_t)255;
  float* pooled = (float*)(ws + off);           off += 8192;
  // y2 region (198 MB) doubles as y1acc (102 MB) — y1acc fully consumed before conv2 writes y2
  unsigned short* y2 = (unsigned short*)(ws + off);
  short* y1acc = (short*)(ws + off);            off += (size_t)32 * 64 * 220 * 220 * 2;
  (void)ws_size; (void)in_sizes; (void)n_in; (void)out_size;

  hipMemsetAsync(sc, 0, 1024, stream);
  k_absmax_x<<<1024, 256, 0, stream>>>(x, NX, &sc->max_x);
  k_absmax_w<<<4, 256, 0, stream>>>(w1, w2, wf1, wf2, sc);
  k_scales<<<1, 1, 0, stream>>>(sc);
  k_quant_x<<<2048, 256, 0, stream>>>(x, xq, NX, sc);
  k_quant_w<<<28, 256, 0, stream>>>(w1, w2, b1, sc, qw1, w2p, bint1);
  k_conv1<<<NCONV1 / 256, 256, 0, stream>>>(xq, qw1, bint1, y1acc, &sc->max1);
  k_fin1<<<1, 64, 0, stream>>>(sc, b2, bint2);
  k_requant<<<NP1 / 8 / 256, 256, 0, stream>>>(y1acc, sc, y1q);
  k_conv2<<<NCONV2 / 256, 256, 0, stream>>>(y1q, w2p, bint2, y2, &sc->max2);
  k_fin2<<<1, 1, 0, stream>>>(sc);
  k_pool<<<2048, 256, 0, stream>>>(y2, sc, pooled);
  k_fc<<<1, 256, 0, stream>>>(pooled, wf1, bf1, wf2, bf2, sc, out);
}